// Round 9
// baseline (606.646 us; speedup 1.0000x reference)
//
#include <hip/hip_runtime.h>
#include <math.h>

#define KAPPA 0.9f
#define ST 68   // LDS row stride (64+4); 68%32=4 -> 2-way aliasing (free)

typedef float vf4 __attribute__((ext_vector_type(4)));  // native vector for nt-loads

__device__ __forceinline__ float relu_f(float v) { return fmaxf(v, 0.0f); }

__device__ __forceinline__ float4 nt_load4(const float* p) {
  vf4 v = __builtin_nontemporal_load((const vf4*)p);
  return make_float4(v.x, v.y, v.z, v.w);
}

// ---------------- Wn_hat = KAPPA * Wn / max(||Wn||_F, 1) ----------------
__global__ __launch_bounds__(256) void wnhat_kernel(const float* __restrict__ Wn,
                                                    float* __restrict__ Wn_hat) {
  __shared__ float red[4];
  int t = threadIdx.x;
  float v[16];
  float s = 0.f;
#pragma unroll
  for (int j = 0; j < 16; ++j) { v[j] = Wn[t + 256 * j]; s += v[j] * v[j]; }
#pragma unroll
  for (int off = 32; off > 0; off >>= 1) s += __shfl_down(s, off, 64);
  if ((t & 63) == 0) red[t >> 6] = s;
  __syncthreads();
  float norm = sqrtf(red[0] + red[1] + red[2] + red[3]);
  float scale = KAPPA / fmaxf(norm, 1.0f);
#pragma unroll
  for (int j = 0; j < 16; ++j) Wn_hat[t + 256 * j] = v[j] * scale;
}

// ---------------- bias_n[n][h] = sum_k Om_n[h][k] * node_data[k][n] ----------------
__global__ __launch_bounds__(256) void bias_n_kernel(const float* __restrict__ node_data,
                                                     const float* __restrict__ Om_n,
                                                     float* __restrict__ bias_n, int N) {
  __shared__ float NdT[64][ST];  // [n][k]
  __shared__ float Om[64][ST];   // [h][k]
  int t = threadIdx.x;
  int n_base = blockIdx.x * 64;
#pragma unroll
  for (int j = 0; j < 16; ++j) {
    int f = t + 256 * j;
    int r = f >> 6, c = f & 63;
    float val = (n_base + c < N) ? node_data[(size_t)r * N + n_base + c] : 0.f;
    NdT[c][r] = val;
    Om[r][c] = Om_n[f];
  }
  __syncthreads();
  int ni = t & 15, h4 = (t >> 4) * 4;
  float acc[4][4] = {};
#pragma unroll 4
  for (int k = 0; k < 64; k += 4) {
    float4 a[4], w[4];
#pragma unroll
    for (int i = 0; i < 4; ++i) a[i] = *(const float4*)&NdT[ni + 16 * i][k];
#pragma unroll
    for (int j = 0; j < 4; ++j) w[j] = *(const float4*)&Om[h4 + j][k];
#pragma unroll
    for (int i = 0; i < 4; ++i)
#pragma unroll
      for (int j = 0; j < 4; ++j)
        acc[i][j] += a[i].x * w[j].x + a[i].y * w[j].y + a[i].z * w[j].z + a[i].w * w[j].w;
  }
#pragma unroll
  for (int i = 0; i < 4; ++i) {
    int n = n_base + ni + 16 * i;
    if (n < N) {
      float4 o = make_float4(acc[i][0], acc[i][1], acc[i][2], acc[i][3]);
      *(float4*)&bias_n[(size_t)n * 64 + h4] = o;
    }
  }
}

// ---------------- CSR build: histogram / scan / scatter ----------------
__global__ void hist_kernel(const int* __restrict__ H, int* __restrict__ count, int E) {
  int e = blockIdx.x * 256 + threadIdx.x;
  if (e < E) atomicAdd(&count[H[e]], 1);
}

__global__ __launch_bounds__(256) void scan_kernel(int* count, int* row_off, int* cursor,
                                                   int N, int E) {
  __shared__ int offs[256];
  __shared__ int sums[256];
  int t = threadIdx.x;
  int chunk = (N + 255) / 256;
  int lo = t * chunk, hi = min(lo + chunk, N);
  int s = 0;
  for (int n = lo; n < hi; ++n) s += count[n];
  sums[t] = s;
  __syncthreads();
  if (t == 0) {
    int run = 0;
    for (int i = 0; i < 256; ++i) { offs[i] = run; run += sums[i]; }
  }
  __syncthreads();
  int run = offs[t];
  for (int n = lo; n < hi; ++n) {
    int c = count[n];   // count and cursor may alias: read first
    row_off[n] = run;
    cursor[n] = run;
    run += c;
  }
  if (t == 0) row_off[N] = E;
}

__global__ void scatter_kernel(const int* __restrict__ H, const int* __restrict__ S,
                               const int* __restrict__ R, int* cursor,
                               int* __restrict__ Ss, int* __restrict__ Rs,
                               int* __restrict__ inv_perm, int E) {
  int e = blockIdx.x * 256 + threadIdx.x;
  if (e < E) {
    int h = H[e];
    int pos = atomicAdd(&cursor[h], 1);
    Ss[pos] = S[e];
    Rs[pos] = R[e];
    inv_perm[e] = pos;
  }
}

// ---------------- bias_s[inv_perm[e]][h] = sum_j Om_e[h][j] * Ra[j][e] ----------------
__global__ __launch_bounds__(256) void bias_build_kernel(const float* __restrict__ Ra,
                                                         const float* __restrict__ Om_e,
                                                         const int* __restrict__ inv_perm,
                                                         float* __restrict__ bias_s, int E) {
  __shared__ float OmT[64][36];  // [h][j]
  __shared__ float RaT[64][36];  // [e][j]
  int t = threadIdx.x;
  int e_base = blockIdx.x * 64;
#pragma unroll
  for (int j = 0; j < 8; ++j) {
    int f = t + 256 * j;  // 2048 = 64h x 32j
    int r = f >> 5, c = f & 31;
    OmT[r][c] = Om_e[f];
  }
#pragma unroll
  for (int j = 0; j < 8; ++j) {
    int f = t + 256 * j;  // 2048 = 32j x 64e
    int r = f >> 6, c = f & 63;
    int ee = e_base + c;
    RaT[c][r] = (ee < E) ? Ra[(size_t)r * E + ee] : 0.f;
  }
  __syncthreads();
  int ei = t & 15, h4 = (t >> 4) * 4;
  float acc[4][4] = {};
#pragma unroll 4
  for (int jj = 0; jj < 32; jj += 4) {
    float4 ra[4], om[4];
#pragma unroll
    for (int i = 0; i < 4; ++i) ra[i] = *(const float4*)&RaT[ei + 16 * i][jj];
#pragma unroll
    for (int j = 0; j < 4; ++j) om[j] = *(const float4*)&OmT[h4 + j][jj];
#pragma unroll
    for (int i = 0; i < 4; ++i)
#pragma unroll
      for (int j = 0; j < 4; ++j)
        acc[i][j] += ra[i].x * om[j].x + ra[i].y * om[j].y + ra[i].z * om[j].z +
                     ra[i].w * om[j].w;
  }
#pragma unroll
  for (int i = 0; i < 4; ++i) {
    int e = e_base + ei + 16 * i;
    if (e < E) {
      int p = inv_perm[e];
      float4 o = make_float4(acc[i][0], acc[i][1], acc[i][2], acc[i][3]);
      *(float4*)&bias_s[(size_t)p * 64 + h4] = o;
    }
  }
}

// ---------------- fused iteration kernel ----------------
// agg (edge gather-sum, registers) + node update + MS/MR of the new X.
// One data tile (Xsh) staged X -> agg -> xnew -> x1 phases. LDS = 3x[64][ST] ~ 52.7KB
// -> 3 blocks/CU.
// FIRST: X==0 => skip X staging and Wn_hat@X; He = relu(bias_s).
// LAST: also run the dense head (V0/V1) on the new X; skip the Xout write.
template <int FIRST, int LAST>
__global__ __launch_bounds__(256) void iter_kernel(
    const float* __restrict__ X, const float* __restrict__ MS_in,
    const float* __restrict__ MR_in, const float* __restrict__ bias_s,
    const int* __restrict__ Ss, const int* __restrict__ Rs,
    const int* __restrict__ row_off, const float* __restrict__ bias_n,
    const float* __restrict__ Wn_hat, const float* __restrict__ Bm,
    const float* __restrict__ W_es, const float* __restrict__ W_er,
    const float* __restrict__ V0_w, const float* __restrict__ V0_b,
    const float* __restrict__ V1_w, const float* __restrict__ V1_b,
    float* __restrict__ Xout, float* __restrict__ MS_out,
    float* __restrict__ MR_out, float* __restrict__ head_out, int N) {
  __shared__ float Wa[64][ST], Wb[64][ST], Xsh[64][ST];
  __shared__ float b0s[64], b1s[64];
  int t = threadIdx.x;
  int n_base = blockIdx.x * 64;
  // stage phase-A weights
#pragma unroll
  for (int j = 0; j < 16; ++j) {
    int f = t + 256 * j;
    int r = f >> 6, c = f & 63;
    Wa[r][c] = Wn_hat[f];
    Wb[r][c] = Bm[f];
  }
  int n = t >> 2, q = t & 3;
  int nd = n_base + n;
  bool ok = nd < N;
  if (!FIRST) {
    // stage X tile
#pragma unroll
    for (int c = 0; c < 4; ++c) {
      float4 xv = make_float4(0, 0, 0, 0);
      if (ok) xv = *(const float4*)&X[(size_t)nd * 64 + q * 16 + 4 * c];
      *(float4*)&Xsh[n][q * 16 + 4 * c] = xv;
    }
  }
  // agg phase: each quad accumulates its node's edge range (registers)
  float4 a0 = make_float4(0, 0, 0, 0), a1 = a0, a2 = a0, a3 = a0;
  if (ok) {
    int r0 = row_off[nd], r1 = row_off[nd + 1];
    for (int p = r0; p < r1; ++p) {
      const float* bp = &bias_s[(size_t)p * 64 + q * 16];
      float4 b0 = nt_load4(bp + 0);
      float4 b1 = nt_load4(bp + 4);
      float4 b2 = nt_load4(bp + 8);
      float4 b3 = nt_load4(bp + 12);
      if (FIRST) {
        a0.x += relu_f(b0.x); a0.y += relu_f(b0.y); a0.z += relu_f(b0.z); a0.w += relu_f(b0.w);
        a1.x += relu_f(b1.x); a1.y += relu_f(b1.y); a1.z += relu_f(b1.z); a1.w += relu_f(b1.w);
        a2.x += relu_f(b2.x); a2.y += relu_f(b2.y); a2.z += relu_f(b2.z); a2.w += relu_f(b2.w);
        a3.x += relu_f(b3.x); a3.y += relu_f(b3.y); a3.z += relu_f(b3.z); a3.w += relu_f(b3.w);
      } else {
        int s = Ss[p], r = Rs[p];
        const float* mp = &MS_in[(size_t)s * 64 + q * 16];
        const float* rp = &MR_in[(size_t)r * 64 + q * 16];
        float4 m0 = *(const float4*)(mp + 0), m1 = *(const float4*)(mp + 4);
        float4 m2 = *(const float4*)(mp + 8), m3 = *(const float4*)(mp + 12);
        float4 r0v = *(const float4*)(rp + 0), r1v = *(const float4*)(rp + 4);
        float4 r2v = *(const float4*)(rp + 8), r3v = *(const float4*)(rp + 12);
        a0.x += relu_f(m0.x + r0v.x + b0.x); a0.y += relu_f(m0.y + r0v.y + b0.y);
        a0.z += relu_f(m0.z + r0v.z + b0.z); a0.w += relu_f(m0.w + r0v.w + b0.w);
        a1.x += relu_f(m1.x + r1v.x + b1.x); a1.y += relu_f(m1.y + r1v.y + b1.y);
        a1.z += relu_f(m1.z + r1v.z + b1.z); a1.w += relu_f(m1.w + r1v.w + b1.w);
        a2.x += relu_f(m2.x + r2v.x + b2.x); a2.y += relu_f(m2.y + r2v.y + b2.y);
        a2.z += relu_f(m2.z + r2v.z + b2.z); a2.w += relu_f(m2.w + r2v.w + b2.w);
        a3.x += relu_f(m3.x + r3v.x + b3.x); a3.y += relu_f(m3.y + r3v.y + b3.y);
        a3.z += relu_f(m3.z + r3v.z + b3.z); a3.w += relu_f(m3.w + r3v.w + b3.w);
      }
    }
  }
  int ni = t & 15, h4 = (t >> 4) * 4;
  float acc[4][4] = {};
  if (!FIRST) {
    __syncthreads();  // Xsh/Wa ready
    // phase A1: acc = Wn_hat @ X
#pragma unroll 4
    for (int k = 0; k < 64; k += 4) {
      float4 xv[4], wv[4];
#pragma unroll
      for (int i = 0; i < 4; ++i) xv[i] = *(const float4*)&Xsh[ni + 16 * i][k];
#pragma unroll
      for (int j = 0; j < 4; ++j) wv[j] = *(const float4*)&Wa[h4 + j][k];
#pragma unroll
      for (int i = 0; i < 4; ++i)
#pragma unroll
        for (int j = 0; j < 4; ++j)
          acc[i][j] += xv[i].x * wv[j].x + xv[i].y * wv[j].y + xv[i].z * wv[j].z +
                       xv[i].w * wv[j].w;
    }
  }
  __syncthreads();  // A1 reads of Xsh done (or initial stage barrier for FIRST)
  // overwrite Xsh with agg
  *(float4*)&Xsh[n][q * 16 + 0] = a0;
  *(float4*)&Xsh[n][q * 16 + 4] = a1;
  *(float4*)&Xsh[n][q * 16 + 8] = a2;
  *(float4*)&Xsh[n][q * 16 + 12] = a3;
  __syncthreads();
  // phase A2: acc += Bm @ agg
#pragma unroll 4
  for (int k = 0; k < 64; k += 4) {
    float4 av[4], bv[4];
#pragma unroll
    for (int i = 0; i < 4; ++i) av[i] = *(const float4*)&Xsh[ni + 16 * i][k];
#pragma unroll
    for (int j = 0; j < 4; ++j) bv[j] = *(const float4*)&Wb[h4 + j][k];
#pragma unroll
    for (int i = 0; i < 4; ++i)
#pragma unroll
      for (int j = 0; j < 4; ++j)
        acc[i][j] += av[i].x * bv[j].x + av[i].y * bv[j].y + av[i].z * bv[j].z +
                     av[i].w * bv[j].w;
  }
  __syncthreads();  // A2 reads of Xsh/Wb done
  // epilogue A: xnew = relu(acc + bias_n) -> Xsh (and Xout unless LAST)
#pragma unroll
  for (int i = 0; i < 4; ++i) {
    int nn = n_base + ni + 16 * i;
    float4 bb = make_float4(0, 0, 0, 0);
    if (nn < N) bb = *(const float4*)&bias_n[(size_t)nn * 64 + h4];
    float x0 = relu_f(acc[i][0] + bb.x);
    float x1 = relu_f(acc[i][1] + bb.y);
    float x2 = relu_f(acc[i][2] + bb.z);
    float x3 = relu_f(acc[i][3] + bb.w);
    if (!LAST && nn < N)
      *(float4*)&Xout[(size_t)nn * 64 + h4] = make_float4(x0, x1, x2, x3);
    Xsh[ni + 16 * i][h4 + 0] = x0;
    Xsh[ni + 16 * i][h4 + 1] = x1;
    Xsh[ni + 16 * i][h4 + 2] = x2;
    Xsh[ni + 16 * i][h4 + 3] = x3;
  }
  // stage phase-B weights (Wa/Wb reads all done)
#pragma unroll
  for (int j = 0; j < 16; ++j) {
    int f = t + 256 * j;
    int r = f >> 6, c = f & 63;
    Wa[r][c] = W_es[f];
    Wb[r][c] = W_er[f];
  }
  __syncthreads();
  // phase B: MS = Wes@xnew, MR = Wer@xnew
  {
    float ma[4][4] = {}, ra[4][4] = {};
#pragma unroll 2
    for (int k = 0; k < 64; k += 4) {
      float4 xv[4], ws[4], wr[4];
#pragma unroll
      for (int i = 0; i < 4; ++i) xv[i] = *(const float4*)&Xsh[ni + 16 * i][k];
#pragma unroll
      for (int j = 0; j < 4; ++j) {
        ws[j] = *(const float4*)&Wa[h4 + j][k];
        wr[j] = *(const float4*)&Wb[h4 + j][k];
      }
#pragma unroll
      for (int i = 0; i < 4; ++i)
#pragma unroll
        for (int j = 0; j < 4; ++j) {
          ma[i][j] += xv[i].x * ws[j].x + xv[i].y * ws[j].y + xv[i].z * ws[j].z +
                      xv[i].w * ws[j].w;
          ra[i][j] += xv[i].x * wr[j].x + xv[i].y * wr[j].y + xv[i].z * wr[j].z +
                      xv[i].w * wr[j].w;
        }
    }
#pragma unroll
    for (int i = 0; i < 4; ++i) {
      int nn = n_base + ni + 16 * i;
      if (nn < N) {
        *(float4*)&MS_out[(size_t)nn * 64 + h4] =
            make_float4(ma[i][0], ma[i][1], ma[i][2], ma[i][3]);
        *(float4*)&MR_out[(size_t)nn * 64 + h4] =
            make_float4(ra[i][0], ra[i][1], ra[i][2], ra[i][3]);
      }
    }
  }
  if (LAST) {
    __syncthreads();  // phase-B reads of Wa/Wb done
#pragma unroll
    for (int j = 0; j < 16; ++j) {
      int f = t + 256 * j;
      int r = f >> 6, c = f & 63;
      Wa[r][c] = V0_w[f];
      Wb[r][c] = V1_w[f];
    }
    if (t < 64) b0s[t] = V0_b[t];
    else if (t < 128) b1s[t - 64] = V1_b[t - 64];
    __syncthreads();
    // phase C: c1 = xnew @ V0^T (registers)
    float c1[4][4] = {};
#pragma unroll 4
    for (int k = 0; k < 64; k += 4) {
      float4 xv[4], wv[4];
#pragma unroll
      for (int i = 0; i < 4; ++i) xv[i] = *(const float4*)&Xsh[ni + 16 * i][k];
#pragma unroll
      for (int j = 0; j < 4; ++j) wv[j] = *(const float4*)&Wa[h4 + j][k];
#pragma unroll
      for (int i = 0; i < 4; ++i)
#pragma unroll
        for (int j = 0; j < 4; ++j)
          c1[i][j] += xv[i].x * wv[j].x + xv[i].y * wv[j].y + xv[i].z * wv[j].z +
                      xv[i].w * wv[j].w;
    }
    __syncthreads();  // phase-C reads of Xsh done
    // x1 = relu(c1 + b0) -> Xsh
#pragma unroll
    for (int i = 0; i < 4; ++i) {
      Xsh[ni + 16 * i][h4 + 0] = relu_f(c1[i][0] + b0s[h4 + 0]);
      Xsh[ni + 16 * i][h4 + 1] = relu_f(c1[i][1] + b0s[h4 + 1]);
      Xsh[ni + 16 * i][h4 + 2] = relu_f(c1[i][2] + b0s[h4 + 2]);
      Xsh[ni + 16 * i][h4 + 3] = relu_f(c1[i][3] + b0s[h4 + 3]);
    }
    __syncthreads();
    // phase D: out = x1 @ V1^T + b1
    float c2[4][4] = {};
#pragma unroll 4
    for (int k = 0; k < 64; k += 4) {
      float4 xv[4], wv[4];
#pragma unroll
      for (int i = 0; i < 4; ++i) xv[i] = *(const float4*)&Xsh[ni + 16 * i][k];
#pragma unroll
      for (int j = 0; j < 4; ++j) wv[j] = *(const float4*)&Wb[h4 + j][k];
#pragma unroll
      for (int i = 0; i < 4; ++i)
#pragma unroll
        for (int j = 0; j < 4; ++j)
          c2[i][j] += xv[i].x * wv[j].x + xv[i].y * wv[j].y + xv[i].z * wv[j].z +
                      xv[i].w * wv[j].w;
    }
#pragma unroll
    for (int i = 0; i < 4; ++i) {
      int nn = n_base + ni + 16 * i;
      if (nn < N) {
        float4 o;
        o.x = c2[i][0] + b1s[h4 + 0];
        o.y = c2[i][1] + b1s[h4 + 1];
        o.z = c2[i][2] + b1s[h4 + 2];
        o.w = c2[i][3] + b1s[h4 + 3];
        *(float4*)&head_out[(size_t)nn * 64 + h4] = o;
      }
    }
  }
}

// ---------------- final edge kernel: pure gather + Om@Ra bias + transpose ----------
// He_logits[h][e] = MS[S[e]][h] + MR[R[e]][h] + (Om_e@Ra)[h][e]
__global__ __launch_bounds__(256) void edge_final_kernel(
    const float* __restrict__ MS, const float* __restrict__ MR,
    const int* __restrict__ S, const int* __restrict__ R,
    const float* __restrict__ Om_e, const float* __restrict__ Ra,
    float* __restrict__ He_out, float* __restrict__ Hel_out, int E) {
  __shared__ float T[64][ST];     // [e][h] gather tile
  __shared__ float pool2[4608];   // OmT[64][36] + RaT[64][36]; later transpose (64*65)
  int t = threadIdx.x;
  int e_base = blockIdx.x * 64;
#pragma unroll
  for (int j = 0; j < 8; ++j) {
    int f = t + 256 * j;  // 2048 = 64h x 32j
    int r = f >> 5, c = f & 31;
    pool2[r * 36 + c] = Om_e[f];
  }
#pragma unroll
  for (int j = 0; j < 8; ++j) {
    int f = t + 256 * j;  // 2048 = 32j x 64e
    int r = f >> 6, c = f & 63;
    int e2 = e_base + c;
    pool2[2304 + c * 36 + r] = (e2 < E) ? Ra[(size_t)r * E + e2] : 0.f;
  }
  // gather MS[S]+MR[R] into T
  {
    int e = t >> 2, q = t & 3;
    int ee = e_base + e;
    int ec = (ee < E) ? ee : 0;
    int s = S[ec], r = R[ec];
    const float* mp = &MS[(size_t)s * 64 + q * 16];
    const float* rp = &MR[(size_t)r * 64 + q * 16];
#pragma unroll
    for (int c = 0; c < 4; ++c) {
      float4 mv = *(const float4*)(mp + 4 * c);
      float4 rv = *(const float4*)(rp + 4 * c);
      *(float4*)&T[e][q * 16 + 4 * c] =
          make_float4(mv.x + rv.x, mv.y + rv.y, mv.z + rv.z, mv.w + rv.w);
    }
  }
  __syncthreads();
  int ei = t & 15, h4 = (t >> 4) * 4;
  float acc[4][4] = {};
#pragma unroll 4
  for (int jj = 0; jj < 32; jj += 4) {
    float4 ra[4], om[4];
#pragma unroll
    for (int i = 0; i < 4; ++i)
      ra[i] = *(const float4*)&pool2[2304 + (ei + 16 * i) * 36 + jj];
#pragma unroll
    for (int j = 0; j < 4; ++j) om[j] = *(const float4*)&pool2[(h4 + j) * 36 + jj];
#pragma unroll
    for (int i = 0; i < 4; ++i)
#pragma unroll
      for (int j = 0; j < 4; ++j)
        acc[i][j] += ra[i].x * om[j].x + ra[i].y * om[j].y + ra[i].z * om[j].z +
                     ra[i].w * om[j].w;
  }
  // add gathered MS+MR
#pragma unroll
  for (int i = 0; i < 4; ++i) {
    float4 tv = *(const float4*)&T[ei + 16 * i][h4];
    acc[i][0] += tv.x;
    acc[i][1] += tv.y;
    acc[i][2] += tv.z;
    acc[i][3] += tv.w;
  }
  __syncthreads();  // done reading pool2 (OmT/RaT) and T
  // transpose via pool2 (stride 65 -> conflict-light column reads)
#pragma unroll
  for (int i = 0; i < 4; ++i)
#pragma unroll
    for (int j = 0; j < 4; ++j)
      pool2[(ei + 16 * i) * 65 + h4 + j] = acc[i][j];
  __syncthreads();
  {
    int e4 = (t & 15) * 4, h0 = t >> 4;
#pragma unroll
    for (int rep = 0; rep < 4; ++rep) {
      int h = h0 + 16 * rep;
      float4 v;
      v.x = pool2[(e4 + 0) * 65 + h];
      v.y = pool2[(e4 + 1) * 65 + h];
      v.z = pool2[(e4 + 2) * 65 + h];
      v.w = pool2[(e4 + 3) * 65 + h];
      size_t idx = (size_t)h * E + e_base + e4;
      if (e_base + e4 < E) {
        *(float4*)&Hel_out[idx] = v;
        float4 u = make_float4(relu_f(v.x), relu_f(v.y), relu_f(v.z), relu_f(v.w));
        *(float4*)&He_out[idx] = u;
      }
    }
  }
}

extern "C" void kernel_launch(void* const* d_in, const int* in_sizes, int n_in,
                              void* d_out, int out_size, void* d_ws, size_t ws_size,
                              hipStream_t stream) {
  const int* R = (const int*)d_in[0];
  const int* S = (const int*)d_in[1];
  const int* H = (const int*)d_in[2];
  const float* node_data = (const float*)d_in[3];
  const float* Ra = (const float*)d_in[4];
  const float* W_es = (const float*)d_in[5];
  const float* W_er = (const float*)d_in[6];
  const float* Om_e = (const float*)d_in[7];
  const float* Wn = (const float*)d_in[8];
  const float* Bm = (const float*)d_in[9];
  const float* Om_n = (const float*)d_in[10];
  const float* V0_w = (const float*)d_in[11];
  const float* V0_b = (const float*)d_in[12];
  const float* V1_w = (const float*)d_in[13];
  const float* V1_b = (const float*)d_in[14];
  const int E = in_sizes[0];
  const int N = in_sizes[3] / 64;
  const size_t N64 = (size_t)N * 64;

  float* ws = (float*)d_ws;
  float* Wn_hat = ws;                    // 4096
  float* bias_n = Wn_hat + 4096;         // N64
  float* X0 = bias_n + N64;              // N64
  float* X1p = X0 + N64;                 // N64
  float* MS_B = X1p + N64;               // N64 (odd-iter MS; final MS)
  float* MR_B = MS_B + N64;              // N64 (odd-iter MR; final MR)
  int* row_off = (int*)(MR_B + N64);     // N+1
  int* cursor = row_off + (N + 1);       // N (doubles as histogram)
  int* Ss = cursor + N;                  // E
  int* Rs = Ss + E;                      // E
  int* inv_perm = Rs + E;                // E

  float* out = (float*)d_out;
  float* out_x = out;                          // [N][64]
  float* out_He = out + N64;                   // [64][E]
  float* out_Hel = out_He + (size_t)64 * E;    // [64][E]
  float* bias_s = out_He;    // He region: sorted-bias scratch during iterations
  float* MS_A = out_Hel;     // Hel region: even-iter MS/MR (dead before edge_final)
  float* MR_A = out_Hel + N64;

  int nb_node = (N + 63) / 64;
  int nb_edge = (E + 63) / 64;
  int nb_flat = (E + 255) / 256;

  hipMemsetAsync(X0, 0, N64 * sizeof(float), stream);
  hipMemsetAsync(cursor, 0, (size_t)N * sizeof(int), stream);
  wnhat_kernel<<<1, 256, 0, stream>>>(Wn, Wn_hat);
  bias_n_kernel<<<nb_node, 256, 0, stream>>>(node_data, Om_n, bias_n, N);
  hist_kernel<<<nb_flat, 256, 0, stream>>>(H, cursor, E);
  scan_kernel<<<1, 256, 0, stream>>>(cursor, row_off, cursor, N, E);
  scatter_kernel<<<nb_flat, 256, 0, stream>>>(H, S, R, cursor, Ss, Rs, inv_perm, E);
  bias_build_kernel<<<nb_edge, 256, 0, stream>>>(Ra, Om_e, inv_perm, bias_s, E);

  float* Xa = X0;
  float* Xb = X1p;
  const float* msi = nullptr;
  const float* mri = nullptr;
  for (int it = 0; it < 8; ++it) {
    float* mso = (it & 1) ? MS_B : MS_A;
    float* mro = (it & 1) ? MR_B : MR_A;
    if (it == 0)
      iter_kernel<1, 0><<<nb_node, 256, 0, stream>>>(
          Xa, nullptr, nullptr, bias_s, Ss, Rs, row_off, bias_n, Wn_hat, Bm, W_es, W_er,
          V0_w, V0_b, V1_w, V1_b, Xb, mso, mro, out_x, N);
    else if (it < 7)
      iter_kernel<0, 0><<<nb_node, 256, 0, stream>>>(
          Xa, msi, mri, bias_s, Ss, Rs, row_off, bias_n, Wn_hat, Bm, W_es, W_er,
          V0_w, V0_b, V1_w, V1_b, Xb, mso, mro, out_x, N);
    else
      iter_kernel<0, 1><<<nb_node, 256, 0, stream>>>(
          Xa, msi, mri, bias_s, Ss, Rs, row_off, bias_n, Wn_hat, Bm, W_es, W_er,
          V0_w, V0_b, V1_w, V1_b, Xb, mso, mro, out_x, N);
    msi = mso;
    mri = mro;
    float* tmp = Xa; Xa = Xb; Xb = tmp;
  }
  // it=7 (odd) wrote MS_B/MR_B in ws; He/Hel regions are free to write now.
  edge_final_kernel<<<nb_edge, 256, 0, stream>>>(MS_B, MR_B, S, R, Om_e, Ra,
                                                 out_He, out_Hel, E);
}

// Round 10
// 459.723 us; speedup vs baseline: 1.3196x; 1.3196x over previous
//
#include <hip/hip_runtime.h>
#include <math.h>

#define KAPPA 0.9f
#define ST 68   // LDS row stride (64+4); 68%32=4 -> 2-way aliasing (free)
#define TN 32   // nodes per iter-kernel tile (smaller tile => 625 blocks => 2.4/CU)

__device__ __forceinline__ float relu_f(float v) { return fmaxf(v, 0.0f); }

// ---------------- Wn_hat = KAPPA * Wn / max(||Wn||_F, 1) ----------------
__global__ __launch_bounds__(256) void wnhat_kernel(const float* __restrict__ Wn,
                                                    float* __restrict__ Wn_hat) {
  __shared__ float red[4];
  int t = threadIdx.x;
  float v[16];
  float s = 0.f;
#pragma unroll
  for (int j = 0; j < 16; ++j) { v[j] = Wn[t + 256 * j]; s += v[j] * v[j]; }
#pragma unroll
  for (int off = 32; off > 0; off >>= 1) s += __shfl_down(s, off, 64);
  if ((t & 63) == 0) red[t >> 6] = s;
  __syncthreads();
  float norm = sqrtf(red[0] + red[1] + red[2] + red[3]);
  float scale = KAPPA / fmaxf(norm, 1.0f);
#pragma unroll
  for (int j = 0; j < 16; ++j) Wn_hat[t + 256 * j] = v[j] * scale;
}

// ---------------- bias_n[n][h] = sum_k Om_n[h][k] * node_data[k][n] ----------------
__global__ __launch_bounds__(256) void bias_n_kernel(const float* __restrict__ node_data,
                                                     const float* __restrict__ Om_n,
                                                     float* __restrict__ bias_n, int N) {
  __shared__ float NdT[64][ST];  // [n][k]
  __shared__ float Om[64][ST];   // [h][k]
  int t = threadIdx.x;
  int n_base = blockIdx.x * 64;
#pragma unroll
  for (int j = 0; j < 16; ++j) {
    int f = t + 256 * j;
    int r = f >> 6, c = f & 63;
    float val = (n_base + c < N) ? node_data[(size_t)r * N + n_base + c] : 0.f;
    NdT[c][r] = val;
    Om[r][c] = Om_n[f];
  }
  __syncthreads();
  int ni = t & 15, h4 = (t >> 4) * 4;
  float acc[4][4] = {};
#pragma unroll 4
  for (int k = 0; k < 64; k += 4) {
    float4 a[4], w[4];
#pragma unroll
    for (int i = 0; i < 4; ++i) a[i] = *(const float4*)&NdT[ni + 16 * i][k];
#pragma unroll
    for (int j = 0; j < 4; ++j) w[j] = *(const float4*)&Om[h4 + j][k];
#pragma unroll
    for (int i = 0; i < 4; ++i)
#pragma unroll
      for (int j = 0; j < 4; ++j)
        acc[i][j] += a[i].x * w[j].x + a[i].y * w[j].y + a[i].z * w[j].z + a[i].w * w[j].w;
  }
#pragma unroll
  for (int i = 0; i < 4; ++i) {
    int n = n_base + ni + 16 * i;
    if (n < N) {
      float4 o = make_float4(acc[i][0], acc[i][1], acc[i][2], acc[i][3]);
      *(float4*)&bias_n[(size_t)n * 64 + h4] = o;
    }
  }
}

// ---------------- CSR build: histogram / scan / scatter ----------------
__global__ void hist_kernel(const int* __restrict__ H, int* __restrict__ count, int E) {
  int e = blockIdx.x * 256 + threadIdx.x;
  if (e < E) atomicAdd(&count[H[e]], 1);
}

__global__ __launch_bounds__(256) void scan_kernel(int* count, int* row_off, int* cursor,
                                                   int N, int E) {
  __shared__ int offs[256];
  __shared__ int sums[256];
  int t = threadIdx.x;
  int chunk = (N + 255) / 256;
  int lo = t * chunk, hi = min(lo + chunk, N);
  int s = 0;
  for (int n = lo; n < hi; ++n) s += count[n];
  sums[t] = s;
  __syncthreads();
  if (t == 0) {
    int run = 0;
    for (int i = 0; i < 256; ++i) { offs[i] = run; run += sums[i]; }
  }
  __syncthreads();
  int run = offs[t];
  for (int n = lo; n < hi; ++n) {
    int c = count[n];   // count and cursor may alias: read first
    row_off[n] = run;
    cursor[n] = run;
    run += c;
  }
  if (t == 0) row_off[N] = E;
}

__global__ void scatter_kernel(const int* __restrict__ H, const int* __restrict__ S,
                               const int* __restrict__ R, int* cursor,
                               int* __restrict__ Ss, int* __restrict__ Rs,
                               int* __restrict__ inv_perm, int E) {
  int e = blockIdx.x * 256 + threadIdx.x;
  if (e < E) {
    int h = H[e];
    int pos = atomicAdd(&cursor[h], 1);
    Ss[pos] = S[e];
    Rs[pos] = R[e];
    inv_perm[e] = pos;
  }
}

// ---------------- bias_s[inv_perm[e]][h] = sum_j Om_e[h][j] * Ra[j][e] ----------------
__global__ __launch_bounds__(256) void bias_build_kernel(const float* __restrict__ Ra,
                                                         const float* __restrict__ Om_e,
                                                         const int* __restrict__ inv_perm,
                                                         float* __restrict__ bias_s, int E) {
  __shared__ float OmT[64][36];  // [h][j]
  __shared__ float RaT[64][36];  // [e][j]
  int t = threadIdx.x;
  int e_base = blockIdx.x * 64;
#pragma unroll
  for (int j = 0; j < 8; ++j) {
    int f = t + 256 * j;  // 2048 = 64h x 32j
    int r = f >> 5, c = f & 31;
    OmT[r][c] = Om_e[f];
  }
#pragma unroll
  for (int j = 0; j < 8; ++j) {
    int f = t + 256 * j;  // 2048 = 32j x 64e
    int r = f >> 6, c = f & 63;
    int ee = e_base + c;
    RaT[c][r] = (ee < E) ? Ra[(size_t)r * E + ee] : 0.f;
  }
  __syncthreads();
  int ei = t & 15, h4 = (t >> 4) * 4;
  float acc[4][4] = {};
#pragma unroll 4
  for (int jj = 0; jj < 32; jj += 4) {
    float4 ra[4], om[4];
#pragma unroll
    for (int i = 0; i < 4; ++i) ra[i] = *(const float4*)&RaT[ei + 16 * i][jj];
#pragma unroll
    for (int j = 0; j < 4; ++j) om[j] = *(const float4*)&OmT[h4 + j][jj];
#pragma unroll
    for (int i = 0; i < 4; ++i)
#pragma unroll
      for (int j = 0; j < 4; ++j)
        acc[i][j] += ra[i].x * om[j].x + ra[i].y * om[j].y + ra[i].z * om[j].z +
                     ra[i].w * om[j].w;
  }
#pragma unroll
  for (int i = 0; i < 4; ++i) {
    int e = e_base + ei + 16 * i;
    if (e < E) {
      int p = inv_perm[e];
      float4 o = make_float4(acc[i][0], acc[i][1], acc[i][2], acc[i][3]);
      *(float4*)&bias_s[(size_t)p * 64 + h4] = o;
    }
  }
}

// ---------------- fused iteration kernel (TN=32 nodes/block, 256 threads) ----------
// agg (8 threads/node, registers) + node update + MS/MR of the new X.
// FIRST: X==0 => skip X staging and Wn_hat@X term.
// LAST: also run the dense head (V0/V1); skip the Xout write.
template <int FIRST, int LAST>
__global__ __launch_bounds__(256) void iter_kernel(
    const float* __restrict__ X, const float* __restrict__ MS_in,
    const float* __restrict__ MR_in, const float* __restrict__ bias_s,
    const int* __restrict__ Ss, const int* __restrict__ Rs,
    const int* __restrict__ row_off, const float* __restrict__ bias_n,
    const float* __restrict__ Wn_hat, const float* __restrict__ Bm,
    const float* __restrict__ W_es, const float* __restrict__ W_er,
    const float* __restrict__ V0_w, const float* __restrict__ V0_b,
    const float* __restrict__ V1_w, const float* __restrict__ V1_b,
    float* __restrict__ Xout, float* __restrict__ MS_out,
    float* __restrict__ MR_out, float* __restrict__ head_out, int N) {
  __shared__ float Wa[64][ST], Wb[64][ST];
  __shared__ float Xsh[TN][ST], Ash[TN][ST];
  __shared__ float b0s[64], b1s[64];
  int t = threadIdx.x;
  int n_base = blockIdx.x * TN;
  // stage phase-A weights
#pragma unroll
  for (int j = 0; j < 16; ++j) {
    int f = t + 256 * j;
    int r = f >> 6, c = f & 63;
    Wa[r][c] = Wn_hat[f];
    Wb[r][c] = Bm[f];
  }
  int n8 = t >> 3;   // node slot 0..31
  int q8 = t & 7;    // 8-float chunk 0..7
  int nd = n_base + n8;
  bool ok = nd < N;
  if (!FIRST) {
    float4 x0 = make_float4(0, 0, 0, 0), x1 = x0;
    if (ok) {
      x0 = *(const float4*)&X[(size_t)nd * 64 + q8 * 8];
      x1 = *(const float4*)&X[(size_t)nd * 64 + q8 * 8 + 4];
    }
    *(float4*)&Xsh[n8][q8 * 8] = x0;
    *(float4*)&Xsh[n8][q8 * 8 + 4] = x1;
  }
  // agg phase: 8 threads per node, each handles 8 floats of the 64-wide row
  float4 a0 = make_float4(0, 0, 0, 0), a1 = a0;
  if (ok) {
    int r0 = row_off[nd], r1 = row_off[nd + 1];
    for (int p = r0; p < r1; ++p) {
      const float* bp = &bias_s[(size_t)p * 64 + q8 * 8];
      float4 b0 = *(const float4*)(bp + 0);
      float4 b1 = *(const float4*)(bp + 4);
      if (FIRST) {
        a0.x += relu_f(b0.x); a0.y += relu_f(b0.y); a0.z += relu_f(b0.z); a0.w += relu_f(b0.w);
        a1.x += relu_f(b1.x); a1.y += relu_f(b1.y); a1.z += relu_f(b1.z); a1.w += relu_f(b1.w);
      } else {
        int s = Ss[p], r = Rs[p];
        const float* mp = &MS_in[(size_t)s * 64 + q8 * 8];
        const float* rp = &MR_in[(size_t)r * 64 + q8 * 8];
        float4 m0 = *(const float4*)(mp + 0), m1 = *(const float4*)(mp + 4);
        float4 r0v = *(const float4*)(rp + 0), r1v = *(const float4*)(rp + 4);
        a0.x += relu_f(m0.x + r0v.x + b0.x); a0.y += relu_f(m0.y + r0v.y + b0.y);
        a0.z += relu_f(m0.z + r0v.z + b0.z); a0.w += relu_f(m0.w + r0v.w + b0.w);
        a1.x += relu_f(m1.x + r1v.x + b1.x); a1.y += relu_f(m1.y + r1v.y + b1.y);
        a1.z += relu_f(m1.z + r1v.z + b1.z); a1.w += relu_f(m1.w + r1v.w + b1.w);
      }
    }
  }
  *(float4*)&Ash[n8][q8 * 8] = a0;
  *(float4*)&Ash[n8][q8 * 8 + 4] = a1;
  __syncthreads();
  // phase A (fused): acc = Wn_hat@X + Bm@agg ; rows = ni, ni+16; cols = h4..h4+3
  int ni = t & 15, h4 = (t >> 4) * 4;
  float acc[2][4] = {};
#pragma unroll 4
  for (int k = 0; k < 64; k += 4) {
    float4 xv[2], av[2], wv[4], bv[4];
#pragma unroll
    for (int i = 0; i < 2; ++i) {
      if (!FIRST) xv[i] = *(const float4*)&Xsh[ni + 16 * i][k];
      av[i] = *(const float4*)&Ash[ni + 16 * i][k];
    }
#pragma unroll
    for (int j = 0; j < 4; ++j) {
      wv[j] = *(const float4*)&Wa[h4 + j][k];
      bv[j] = *(const float4*)&Wb[h4 + j][k];
    }
#pragma unroll
    for (int i = 0; i < 2; ++i)
#pragma unroll
      for (int j = 0; j < 4; ++j) {
        float v = av[i].x * bv[j].x + av[i].y * bv[j].y + av[i].z * bv[j].z +
                  av[i].w * bv[j].w;
        if (!FIRST)
          v += xv[i].x * wv[j].x + xv[i].y * wv[j].y + xv[i].z * wv[j].z +
               xv[i].w * wv[j].w;
        acc[i][j] += v;
      }
  }
  __syncthreads();  // phase-A reads of Xsh/Ash/Wa/Wb done
  // epilogue A: xnew = relu(acc + bias_n) -> Xsh (and Xout unless LAST)
#pragma unroll
  for (int i = 0; i < 2; ++i) {
    int nn = n_base + ni + 16 * i;
    float4 bb = make_float4(0, 0, 0, 0);
    if (nn < N) bb = *(const float4*)&bias_n[(size_t)nn * 64 + h4];
    float x0 = relu_f(acc[i][0] + bb.x);
    float x1 = relu_f(acc[i][1] + bb.y);
    float x2 = relu_f(acc[i][2] + bb.z);
    float x3 = relu_f(acc[i][3] + bb.w);
    if (!LAST && nn < N)
      *(float4*)&Xout[(size_t)nn * 64 + h4] = make_float4(x0, x1, x2, x3);
    *(float4*)&Xsh[ni + 16 * i][h4] = make_float4(x0, x1, x2, x3);
  }
  // stage phase-B weights (Wa/Wb reads all done at last barrier)
#pragma unroll
  for (int j = 0; j < 16; ++j) {
    int f = t + 256 * j;
    int r = f >> 6, c = f & 63;
    Wa[r][c] = W_es[f];
    Wb[r][c] = W_er[f];
  }
  __syncthreads();
  // phase B: MS = Wes@xnew, MR = Wer@xnew
  {
    float ma[2][4] = {}, ra[2][4] = {};
#pragma unroll 4
    for (int k = 0; k < 64; k += 4) {
      float4 xv[2], ws[4], wr[4];
#pragma unroll
      for (int i = 0; i < 2; ++i) xv[i] = *(const float4*)&Xsh[ni + 16 * i][k];
#pragma unroll
      for (int j = 0; j < 4; ++j) {
        ws[j] = *(const float4*)&Wa[h4 + j][k];
        wr[j] = *(const float4*)&Wb[h4 + j][k];
      }
#pragma unroll
      for (int i = 0; i < 2; ++i)
#pragma unroll
        for (int j = 0; j < 4; ++j) {
          ma[i][j] += xv[i].x * ws[j].x + xv[i].y * ws[j].y + xv[i].z * ws[j].z +
                      xv[i].w * ws[j].w;
          ra[i][j] += xv[i].x * wr[j].x + xv[i].y * wr[j].y + xv[i].z * wr[j].z +
                      xv[i].w * wr[j].w;
        }
    }
#pragma unroll
    for (int i = 0; i < 2; ++i) {
      int nn = n_base + ni + 16 * i;
      if (nn < N) {
        *(float4*)&MS_out[(size_t)nn * 64 + h4] =
            make_float4(ma[i][0], ma[i][1], ma[i][2], ma[i][3]);
        *(float4*)&MR_out[(size_t)nn * 64 + h4] =
            make_float4(ra[i][0], ra[i][1], ra[i][2], ra[i][3]);
      }
    }
  }
  if (LAST) {
    __syncthreads();  // phase-B reads of Wa/Wb done
#pragma unroll
    for (int j = 0; j < 16; ++j) {
      int f = t + 256 * j;
      int r = f >> 6, c = f & 63;
      Wa[r][c] = V0_w[f];
      Wb[r][c] = V1_w[f];
    }
    if (t < 64) b0s[t] = V0_b[t];
    else if (t < 128) b1s[t - 64] = V1_b[t - 64];
    __syncthreads();
    // phase C: c1 = xnew @ V0^T (registers)
    float c1[2][4] = {};
#pragma unroll 4
    for (int k = 0; k < 64; k += 4) {
      float4 xv[2], wv[4];
#pragma unroll
      for (int i = 0; i < 2; ++i) xv[i] = *(const float4*)&Xsh[ni + 16 * i][k];
#pragma unroll
      for (int j = 0; j < 4; ++j) wv[j] = *(const float4*)&Wa[h4 + j][k];
#pragma unroll
      for (int i = 0; i < 2; ++i)
#pragma unroll
        for (int j = 0; j < 4; ++j)
          c1[i][j] += xv[i].x * wv[j].x + xv[i].y * wv[j].y + xv[i].z * wv[j].z +
                      xv[i].w * wv[j].w;
    }
    __syncthreads();  // phase-C reads of Xsh done
    // x1 = relu(c1 + b0) -> Xsh
#pragma unroll
    for (int i = 0; i < 2; ++i) {
      float4 o;
      o.x = relu_f(c1[i][0] + b0s[h4 + 0]);
      o.y = relu_f(c1[i][1] + b0s[h4 + 1]);
      o.z = relu_f(c1[i][2] + b0s[h4 + 2]);
      o.w = relu_f(c1[i][3] + b0s[h4 + 3]);
      *(float4*)&Xsh[ni + 16 * i][h4] = o;
    }
    __syncthreads();
    // phase D: out = x1 @ V1^T + b1
    float c2[2][4] = {};
#pragma unroll 4
    for (int k = 0; k < 64; k += 4) {
      float4 xv[2], wv[4];
#pragma unroll
      for (int i = 0; i < 2; ++i) xv[i] = *(const float4*)&Xsh[ni + 16 * i][k];
#pragma unroll
      for (int j = 0; j < 4; ++j) wv[j] = *(const float4*)&Wb[h4 + j][k];
#pragma unroll
      for (int i = 0; i < 2; ++i)
#pragma unroll
        for (int j = 0; j < 4; ++j)
          c2[i][j] += xv[i].x * wv[j].x + xv[i].y * wv[j].y + xv[i].z * wv[j].z +
                      xv[i].w * wv[j].w;
    }
#pragma unroll
    for (int i = 0; i < 2; ++i) {
      int nn = n_base + ni + 16 * i;
      if (nn < N) {
        float4 o;
        o.x = c2[i][0] + b1s[h4 + 0];
        o.y = c2[i][1] + b1s[h4 + 1];
        o.z = c2[i][2] + b1s[h4 + 2];
        o.w = c2[i][3] + b1s[h4 + 3];
        *(float4*)&head_out[(size_t)nn * 64 + h4] = o;
      }
    }
  }
}

// ---------------- final edge kernel: pure gather + Om@Ra bias + transpose ----------
// He_logits[h][e] = MS[S[e]][h] + MR[R[e]][h] + (Om_e@Ra)[h][e]
__global__ __launch_bounds__(256) void edge_final_kernel(
    const float* __restrict__ MS, const float* __restrict__ MR,
    const int* __restrict__ S, const int* __restrict__ R,
    const float* __restrict__ Om_e, const float* __restrict__ Ra,
    float* __restrict__ He_out, float* __restrict__ Hel_out, int E) {
  __shared__ float T[64][ST];     // [e][h] gather tile
  __shared__ float pool2[4608];   // OmT[64][36] + RaT[64][36]; later transpose (64*65)
  int t = threadIdx.x;
  int e_base = blockIdx.x * 64;
#pragma unroll
  for (int j = 0; j < 8; ++j) {
    int f = t + 256 * j;  // 2048 = 64h x 32j
    int r = f >> 5, c = f & 31;
    pool2[r * 36 + c] = Om_e[f];
  }
#pragma unroll
  for (int j = 0; j < 8; ++j) {
    int f = t + 256 * j;  // 2048 = 32j x 64e
    int r = f >> 6, c = f & 63;
    int e2 = e_base + c;
    pool2[2304 + c * 36 + r] = (e2 < E) ? Ra[(size_t)r * E + e2] : 0.f;
  }
  // gather MS[S]+MR[R] into T
  {
    int e = t >> 2, q = t & 3;
    int ee = e_base + e;
    int ec = (ee < E) ? ee : 0;
    int s = S[ec], r = R[ec];
    const float* mp = &MS[(size_t)s * 64 + q * 16];
    const float* rp = &MR[(size_t)r * 64 + q * 16];
#pragma unroll
    for (int c = 0; c < 4; ++c) {
      float4 mv = *(const float4*)(mp + 4 * c);
      float4 rv = *(const float4*)(rp + 4 * c);
      *(float4*)&T[e][q * 16 + 4 * c] =
          make_float4(mv.x + rv.x, mv.y + rv.y, mv.z + rv.z, mv.w + rv.w);
    }
  }
  __syncthreads();
  int ei = t & 15, h4 = (t >> 4) * 4;
  float acc[4][4] = {};
#pragma unroll 4
  for (int jj = 0; jj < 32; jj += 4) {
    float4 ra[4], om[4];
#pragma unroll
    for (int i = 0; i < 4; ++i)
      ra[i] = *(const float4*)&pool2[2304 + (ei + 16 * i) * 36 + jj];
#pragma unroll
    for (int j = 0; j < 4; ++j) om[j] = *(const float4*)&pool2[(h4 + j) * 36 + jj];
#pragma unroll
    for (int i = 0; i < 4; ++i)
#pragma unroll
      for (int j = 0; j < 4; ++j)
        acc[i][j] += ra[i].x * om[j].x + ra[i].y * om[j].y + ra[i].z * om[j].z +
                     ra[i].w * om[j].w;
  }
  // add gathered MS+MR
#pragma unroll
  for (int i = 0; i < 4; ++i) {
    float4 tv = *(const float4*)&T[ei + 16 * i][h4];
    acc[i][0] += tv.x;
    acc[i][1] += tv.y;
    acc[i][2] += tv.z;
    acc[i][3] += tv.w;
  }
  __syncthreads();  // done reading pool2 (OmT/RaT) and T
  // transpose via pool2 (stride 65 -> conflict-light column reads)
#pragma unroll
  for (int i = 0; i < 4; ++i)
#pragma unroll
    for (int j = 0; j < 4; ++j)
      pool2[(ei + 16 * i) * 65 + h4 + j] = acc[i][j];
  __syncthreads();
  {
    int e4 = (t & 15) * 4, h0 = t >> 4;
#pragma unroll
    for (int rep = 0; rep < 4; ++rep) {
      int h = h0 + 16 * rep;
      float4 v;
      v.x = pool2[(e4 + 0) * 65 + h];
      v.y = pool2[(e4 + 1) * 65 + h];
      v.z = pool2[(e4 + 2) * 65 + h];
      v.w = pool2[(e4 + 3) * 65 + h];
      size_t idx = (size_t)h * E + e_base + e4;
      if (e_base + e4 < E) {
        *(float4*)&Hel_out[idx] = v;
        float4 u = make_float4(relu_f(v.x), relu_f(v.y), relu_f(v.z), relu_f(v.w));
        *(float4*)&He_out[idx] = u;
      }
    }
  }
}

extern "C" void kernel_launch(void* const* d_in, const int* in_sizes, int n_in,
                              void* d_out, int out_size, void* d_ws, size_t ws_size,
                              hipStream_t stream) {
  const int* R = (const int*)d_in[0];
  const int* S = (const int*)d_in[1];
  const int* H = (const int*)d_in[2];
  const float* node_data = (const float*)d_in[3];
  const float* Ra = (const float*)d_in[4];
  const float* W_es = (const float*)d_in[5];
  const float* W_er = (const float*)d_in[6];
  const float* Om_e = (const float*)d_in[7];
  const float* Wn = (const float*)d_in[8];
  const float* Bm = (const float*)d_in[9];
  const float* Om_n = (const float*)d_in[10];
  const float* V0_w = (const float*)d_in[11];
  const float* V0_b = (const float*)d_in[12];
  const float* V1_w = (const float*)d_in[13];
  const float* V1_b = (const float*)d_in[14];
  const int E = in_sizes[0];
  const int N = in_sizes[3] / 64;
  const size_t N64 = (size_t)N * 64;

  float* ws = (float*)d_ws;
  float* Wn_hat = ws;                    // 4096
  float* bias_n = Wn_hat + 4096;         // N64
  float* X0 = bias_n + N64;              // N64
  float* X1p = X0 + N64;                 // N64
  float* MS_B = X1p + N64;               // N64 (odd-iter MS; final MS)
  float* MR_B = MS_B + N64;              // N64 (odd-iter MR; final MR)
  int* row_off = (int*)(MR_B + N64);     // N+1
  int* cursor = row_off + (N + 1);       // N (doubles as histogram)
  int* Ss = cursor + N;                  // E
  int* Rs = Ss + E;                      // E
  int* inv_perm = Rs + E;                // E

  float* out = (float*)d_out;
  float* out_x = out;                          // [N][64]
  float* out_He = out + N64;                   // [64][E]
  float* out_Hel = out_He + (size_t)64 * E;    // [64][E]
  float* bias_s = out_He;    // He region: sorted-bias scratch during iterations
  float* MS_A = out_Hel;     // Hel region: even-iter MS/MR (dead before edge_final)
  float* MR_A = out_Hel + N64;

  int nb_node = (N + 63) / 64;
  int nb_iter = (N + TN - 1) / TN;
  int nb_edge = (E + 63) / 64;
  int nb_flat = (E + 255) / 256;

  hipMemsetAsync(X0, 0, N64 * sizeof(float), stream);
  hipMemsetAsync(cursor, 0, (size_t)N * sizeof(int), stream);
  wnhat_kernel<<<1, 256, 0, stream>>>(Wn, Wn_hat);
  bias_n_kernel<<<nb_node, 256, 0, stream>>>(node_data, Om_n, bias_n, N);
  hist_kernel<<<nb_flat, 256, 0, stream>>>(H, cursor, E);
  scan_kernel<<<1, 256, 0, stream>>>(cursor, row_off, cursor, N, E);
  scatter_kernel<<<nb_flat, 256, 0, stream>>>(H, S, R, cursor, Ss, Rs, inv_perm, E);
  bias_build_kernel<<<nb_edge, 256, 0, stream>>>(Ra, Om_e, inv_perm, bias_s, E);

  float* Xa = X0;
  float* Xb = X1p;
  const float* msi = nullptr;
  const float* mri = nullptr;
  for (int it = 0; it < 8; ++it) {
    float* mso = (it & 1) ? MS_B : MS_A;
    float* mro = (it & 1) ? MR_B : MR_A;
    if (it == 0)
      iter_kernel<1, 0><<<nb_iter, 256, 0, stream>>>(
          Xa, nullptr, nullptr, bias_s, Ss, Rs, row_off, bias_n, Wn_hat, Bm, W_es, W_er,
          V0_w, V0_b, V1_w, V1_b, Xb, mso, mro, out_x, N);
    else if (it < 7)
      iter_kernel<0, 0><<<nb_iter, 256, 0, stream>>>(
          Xa, msi, mri, bias_s, Ss, Rs, row_off, bias_n, Wn_hat, Bm, W_es, W_er,
          V0_w, V0_b, V1_w, V1_b, Xb, mso, mro, out_x, N);
    else
      iter_kernel<0, 1><<<nb_iter, 256, 0, stream>>>(
          Xa, msi, mri, bias_s, Ss, Rs, row_off, bias_n, Wn_hat, Bm, W_es, W_er,
          V0_w, V0_b, V1_w, V1_b, Xb, mso, mro, out_x, N);
    msi = mso;
    mri = mro;
    float* tmp = Xa; Xa = Xb; Xb = tmp;
  }
  // it=7 (odd) wrote MS_B/MR_B in ws; He/Hel regions are free to write now.
  edge_final_kernel<<<nb_edge, 256, 0, stream>>>(MS_B, MR_B, S, R, Om_e, Ra,
                                                 out_He, out_Hel, E);
}